// Round 7
// baseline (6597.417 us; speedup 1.0000x reference)
//
#include <hip/hip_runtime.h>
#include <hip/hip_bf16.h>
#include <stdint.h>

#define SQ   2048
#define NB   8
#define G4   1024
#define NROW 16384   // SQ*NB

typedef float f32x4 __attribute__((ext_vector_type(4)));
typedef short bf16x8 __attribute__((ext_vector_type(8)));
typedef uint32_t u32;
typedef unsigned long long u64;

// ---------------- helpers ----------------
__device__ __forceinline__ f32x4 mfma16(bf16x8 a, bf16x8 b, f32x4 c) {
  return __builtin_amdgcn_mfma_f32_16x16x32_bf16(a, b, c, 0, 0, 0);
}
__device__ __forceinline__ u32 pk_bf16(float lo, float hi) {
  u32 r;
  asm("v_cvt_pk_bf16_f32 %0, %1, %2" : "=v"(r) : "v"(lo), "v"(hi));
  return r;
}
__device__ __forceinline__ float bf_lo(u32 u){ union{u32 a; float f;} x; x.a = u << 16;        return x.f; }
__device__ __forceinline__ float bf_hi(u32 u){ union{u32 a; float f;} x; x.a = u & 0xffff0000u; return x.f; }

__device__ __forceinline__ float sigm(float x)   { return 1.0f / (1.0f + __expf(-x)); }
__device__ __forceinline__ float tanh_f(float x) { return 1.0f - 2.0f / (__expf(2.0f * x) + 1.0f); }

// Opaque touch: turns the value's def into an inline-asm output so LLVM
// cannot rematerialize it by re-loading from (readonly) memory inside the
// step loop. Pure register-allocation constraint; emits no instructions.
#define PIN(x) asm volatile("" : "+v"(x))

// Fast-mirror ops: sc0 = bypass L1, hit the XCD-shared L2. Visibility is
// only guaranteed within one XCD — every use is tag-guarded with a slow
// (agent-scope, MALL) fallback, so cross-XCD placement stays correct.
__device__ __forceinline__ u64 ld_fast(const u64* p) {
  u64 v;
  asm volatile("global_load_dwordx2 %0, %1, off sc0\n\ts_waitcnt vmcnt(0)"
               : "=v"(v) : "v"(p) : "memory");
  return v;
}
__device__ __forceinline__ void st_fast(u64* p, u64 v) {
  asm volatile("global_store_dwordx2 %0, %1, off sc0" :: "v"(p), "v"(v) : "memory");
}

// =====================================================================
// Kernel 1: x_proj = x @ Wih^T + bih  -> bf16, layout [dir][m=t*8+b][1024]
// (unchanged from the version that passed R2/R5/R6)
// =====================================================================
__global__ __launch_bounds__(256) void xproj_gemm(
    const float* __restrict__ x,
    const float* __restrict__ WihF, const float* __restrict__ bihF,
    const float* __restrict__ WihB, const float* __restrict__ bihB,
    uint16_t* __restrict__ xp)
{
  const int dir = blockIdx.z;
  const float* Wih = dir ? WihB : WihF;
  const float* bih = dir ? bihB : bihF;
  char* xpd = (char*)xp + (size_t)dir * ((size_t)NROW * G4 * 2);

  const int g0 = blockIdx.y * 128;
  const int m0 = blockIdx.x * 128;

  __shared__ union {
    struct { short A[128 * 72]; short B[128 * 72]; } s;  // 144B row pitch
    short T[128 * 136];                                  // transpose stage
  } u;
  __shared__ float biasS[128];

  const int tid  = threadIdx.x;
  const int lane = tid & 63;
  const int w    = tid >> 6;
  const int wg   = w >> 1;
  const int wm   = w & 1;
  const int l15  = lane & 15;
  const int l4   = lane >> 4;

  if (tid < 128) biasS[tid] = bih[g0 + tid];

  f32x4 acc[4][4] = {};

  const int r_st = tid >> 1;
  const int half = tid & 1;
  const int mrow_st = m0 + r_st;
  const int xb = mrow_st & 7;
  const int xt = mrow_st >> 3;
  const float* xrow = x + ((size_t)xb * SQ + xt) * 256;
  const float* wrow = Wih + (size_t)(g0 + r_st) * 256;

  for (int s = 0; s < 4; ++s) {
    const int k0 = s * 64;
    __syncthreads();
    {
      const float* srcA = wrow + k0 + half * 32;
      const float* srcB = xrow + k0 + half * 32;
      short* dstA = u.s.A + r_st * 72 + half * 32;
      short* dstB = u.s.B + r_st * 72 + half * 32;
      #pragma unroll
      for (int j = 0; j < 4; ++j) {
        f32x4 a0 = *(const f32x4*)(srcA + j * 8);
        f32x4 a1 = *(const f32x4*)(srcA + j * 8 + 4);
        uint4 pa = { pk_bf16(a0.x, a0.y), pk_bf16(a0.z, a0.w),
                     pk_bf16(a1.x, a1.y), pk_bf16(a1.z, a1.w) };
        *(uint4*)(dstA + j * 8) = pa;
        f32x4 b0 = *(const f32x4*)(srcB + j * 8);
        f32x4 b1 = *(const f32x4*)(srcB + j * 8 + 4);
        uint4 pb = { pk_bf16(b0.x, b0.y), pk_bf16(b0.z, b0.w),
                     pk_bf16(b1.x, b1.y), pk_bf16(b1.z, b1.w) };
        *(uint4*)(dstB + j * 8) = pb;
      }
    }
    __syncthreads();
    #pragma unroll
    for (int kt = 0; kt < 2; ++kt) {
      bf16x8 aF[4], bF[4];
      #pragma unroll
      for (int i = 0; i < 4; ++i) {
        const int ar = wg * 64 + i * 16 + l15;
        const int br = wm * 64 + i * 16 + l15;
        aF[i] = *(const bf16x8*)(u.s.A + ar * 72 + kt * 32 + l4 * 8);
        bF[i] = *(const bf16x8*)(u.s.B + br * 72 + kt * 32 + l4 * 8);
      }
      #pragma unroll
      for (int i = 0; i < 4; ++i)
        #pragma unroll
        for (int j = 0; j < 4; ++j)
          acc[i][j] = mfma16(aF[i], bF[j], acc[i][j]);
    }
  }

  __syncthreads();
  #pragma unroll
  for (int i = 0; i < 4; ++i) {
    const f32x4 bv = *(const f32x4*)(biasS + wg * 64 + i * 16 + l4 * 4);
    #pragma unroll
    for (int j = 0; j < 4; ++j) {
      f32x4 v = acc[i][j];
      v.x += bv.x; v.y += bv.y; v.z += bv.z; v.w += bv.w;
      const int mrow = wm * 64 + j * 16 + l15;
      const int gcol = wg * 64 + i * 16 + l4 * 4;
      uint2 p; p.x = pk_bf16(v.x, v.y); p.y = pk_bf16(v.z, v.w);
      *(uint2*)(u.T + mrow * 136 + gcol) = p;
    }
  }
  __syncthreads();
  {
    const char* trow = (const char*)(u.T + r_st * 136);
    char* orow = xpd + (size_t)(m0 + r_st) * 2048 + g0 * 2;
    #pragma unroll
    for (int j = 0; j < 8; ++j) {
      const int local = half * 128 + j * 16;
      uint4 v = *(const uint4*)(trow + local);
      *(uint4*)(orow + local) = v;
    }
  }
}

// =====================================================================
// Kernel 2: BiLSTM scan. 2 WGs/dir x 8 waves (512 thr). Wave w owns all
// 4 gates x 16 h-dims: weights = 128 VGPRs/lane, PINNED via opaque asm
// (R6 showed LLVM otherwise sinks the loads into the loop -> 256KB/step
// L2 re-stream, the 4400cyc/step bottleneck). Exchange: each lane
// publishes ONE {2bf16|tag} word to a fast mirror (same-XCD L2, sc0) and
// the proven slow mirror (agent/MALL atomic); readers spin fast, fall
// back to slow after 8 misses, latch slow-mode after 4 slow-wins.
// =====================================================================
template<int HALF>
__device__ __forceinline__ void lstm_body(
    const float* __restrict__ Whh, const uint16_t* __restrict__ xpd,
    float* __restrict__ out,
    u64* exf_me, u64* exs_me, const u64* exf_pt, const u64* exs_pt, int dir,
    uint16_t (*hT)[8][136], uint16_t (*hP)[8][136])
{
  const int tid  = threadIdx.x;
  const int lane = tid & 63;
  const int w    = tid >> 6;          // wave 0..7
  const int l15  = lane & 15;
  const int l4   = lane >> 4;
  const int bcl  = lane & 7;          // batch this lane serves
  const int qsel = (lane >> 3) & 1;   // duplicate-column half select

  // ---- persistent weights: gate g, k-block kt; rows g*256 + HALF*128 + w*16
  bf16x8 W[4][8];
  #pragma unroll
  for (int g = 0; g < 4; ++g) {
    const int row = g * 256 + HALF * 128 + w * 16 + l15;
    const float* src = Whh + (size_t)row * 256 + l4 * 8;
    #pragma unroll
    for (int kt = 0; kt < 8; ++kt) {
      f32x4 v0 = *(const f32x4*)(src + kt * 32);
      f32x4 v1 = *(const f32x4*)(src + kt * 32 + 4);
      union { bf16x8 v; u32 u[4]; } pk;
      pk.u[0] = pk_bf16(v0.x, v0.y); pk.u[1] = pk_bf16(v0.z, v0.w);
      pk.u[2] = pk_bf16(v1.x, v1.y); pk.u[3] = pk_bf16(v1.z, v1.w);
      W[g][kt] = pk.v;
      PIN(W[g][kt]);                   // <- forbid remat/sink into loop
    }
  }

  const int d0   = w * 16 + l4 * 4 + qsel * 2;     // local dim pair this lane owns
  const int word = bcl * 64 + (d0 >> 1);           // publish word index (bijective)
  float c0 = 0.0f, c1 = 0.0f;

  // prologue: xp for step 0 (2 bf16 per gate)
  u32 xq[4], xqn[4];
  {
    const int tt0 = dir ? SQ - 1 : 0;
    const uint16_t* xr = xpd + (size_t)(tt0 * 8 + bcl) * 1024 + HALF * 128 + d0;
    #pragma unroll
    for (int g = 0; g < 4; ++g) xq[g] = *(const u32*)(xr + g * 256);
  }

  int thr = 8;        // fast tries before probing slow; 0 = latched slow-mode
  int slowWins = 0;

  #pragma unroll 1
  for (int t = 0; t < SQ; ++t) {
    const int tt = dir ? (SQ - 1 - t) : t;

    // ---- poll partner word, stage into LDS
    if (t > 0) {
      const u32 want = (u32)t;
      const size_t off = (size_t)((t - 1) & 1) * 512 + tid;
      u64 pw;
      int tries = 0;
      for (;;) {
        if (tries < thr)
          pw = ld_fast(exf_pt + off);
        else
          pw = __hip_atomic_load(exs_pt + off, __ATOMIC_RELAXED,
                                 __HIP_MEMORY_SCOPE_AGENT);
        if ((u32)pw == want) break;
        ++tries;
      }
      if (thr > 0 && tries >= thr) { if (++slowWins >= 4) thr = 0; }
      *(u32*)&hP[(t - 1) & 1][w][lane * 2] = (u32)(pw >> 32);
    }
    asm volatile("s_waitcnt lgkmcnt(0)" ::: "memory");
    __builtin_amdgcn_s_barrier();

    // ---- issue next step's xp loads NOW (drained harmlessly by next poll)
    {
      const int tn = (t + 1 < SQ) ? t + 1 : SQ - 1;
      const int ttn = dir ? (SQ - 1 - tn) : tn;
      const uint16_t* xr = xpd + (size_t)(ttn * 8 + bcl) * 1024 + HALF * 128 + d0;
      #pragma unroll
      for (int g = 0; g < 4; ++g) xqn[g] = *(const u32*)(xr + g * 256);
    }

    // ---- gates = Whh * h (32 MFMAs; B-frags from LDS, both halves)
    f32x4 acc[4] = {};
    if (t > 0) {
      #pragma unroll
      for (int ko = 0; ko < 4; ++ko) {
        const bf16x8 bO = *(const bf16x8*)&hT[t & 1][bcl][ko * 32 + l4 * 8];
        #pragma unroll
        for (int g = 0; g < 4; ++g) acc[g] = mfma16(W[g][HALF * 4 + ko], bO, acc[g]);
        const bf16x8 bP = *(const bf16x8*)&hP[(t - 1) & 1][bcl][ko * 32 + l4 * 8];
        #pragma unroll
        for (int g = 0; g < 4; ++g) acc[g] = mfma16(W[g][(1 - HALF) * 4 + ko], bP, acc[g]);
      }
    }

    // ---- epilogue (wave-local: all 4 gates present)
    float P0[4], P1[4];
    #pragma unroll
    for (int g = 0; g < 4; ++g) {
      P0[g] = (qsel ? acc[g].z : acc[g].x) + bf_lo(xq[g]);
      P1[g] = (qsel ? acc[g].w : acc[g].y) + bf_hi(xq[g]);
    }
    const float i0 = sigm(P0[0]), f0 = sigm(P0[1]), g0v = tanh_f(P0[2]), o0 = sigm(P0[3]);
    const float i1 = sigm(P1[0]), f1 = sigm(P1[1]), g1v = tanh_f(P1[2]), o1 = sigm(P1[3]);
    c0 = f0 * c0 + i0 * g0v;
    c1 = f1 * c1 + i1 * g1v;
    const float h0 = o0 * tanh_f(c0);
    const float h1 = o1 * tanh_f(c1);

    // ---- publish FIRST (partner's critical path), then local state, then out
    const u32 h01 = pk_bf16(h0, h1);
    const u64 pub = ((u64)h01 << 32) | (u64)(u32)(t + 1);
    st_fast(exf_me + (size_t)(t & 1) * 512 + word, pub);
    __hip_atomic_store(exs_me + (size_t)(t & 1) * 512 + word, pub,
                       __ATOMIC_RELAXED, __HIP_MEMORY_SCOPE_AGENT);
    *(u32*)&hT[(t + 1) & 1][bcl][d0] = h01;
    *(float2*)(out + ((size_t)bcl * SQ + tt) * 512 + dir * 256 + HALF * 128 + d0) =
        make_float2(h0, h1);

    #pragma unroll
    for (int g = 0; g < 4; ++g) xq[g] = xqn[g];
  }
}

__global__ __launch_bounds__(512, 2) void lstm_rec(
    const float* __restrict__ WhhF, const float* __restrict__ WhhB,
    const uint16_t* __restrict__ xp, float* __restrict__ out,
    u64* exs, u64* exf)
{
  __shared__ uint16_t hT[2][8][136];   // own half h, double-buffered (272B pitch)
  __shared__ uint16_t hP[2][8][136];   // partner half h, double-buffered

  const int bid  = blockIdx.x;
  const int dir  = bid & 7;            // pair (bid, bid+8) -> same XCD (round-robin)
  const int half = bid >> 3;
  if (dir > 1) return;                 // 12 idle blocks exit

  const float* Whh = dir ? WhhB : WhhF;
  const uint16_t* xpd = xp + (size_t)dir * NROW * G4;
  const size_t me = (size_t)(dir * 2 + half) * 1024;        // 2 slots x 512 words
  const size_t pt = (size_t)(dir * 2 + (1 - half)) * 1024;

  if (half == 0)
    lstm_body<0>(Whh, xpd, out, exf + me, exs + me, exf + pt, exs + pt, dir, hT, hP);
  else
    lstm_body<1>(Whh, xpd, out, exf + me, exs + me, exf + pt, exs + pt, dir, hT, hP);
}

// =====================================================================
extern "C" void kernel_launch(void* const* d_in, const int* in_sizes, int n_in,
                              void* d_out, int out_size, void* d_ws, size_t ws_size,
                              hipStream_t stream) {
  const float* x    = (const float*)d_in[0];
  const float* WihF = (const float*)d_in[1];
  const float* bihF = (const float*)d_in[2];
  const float* WhhF = (const float*)d_in[3];
  const float* WihB = (const float*)d_in[4];
  const float* bihB = (const float*)d_in[5];
  const float* WhhB = (const float*)d_in[6];
  float* out = (float*)d_out;

  const size_t XPB = (size_t)2 * NROW * G4 * 2;     // 64 MiB bf16 x-projection
  const size_t EXB = (size_t)4096 * sizeof(u64);    // 32 KiB per mirror
  if (ws_size < XPB + 2 * EXB) return;
  uint16_t* xpw = (uint16_t*)d_ws;
  u64* exs = (u64*)((char*)d_ws + XPB);             // slow mirror (agent/MALL)
  u64* exf = (u64*)((char*)d_ws + XPB + EXB);       // fast mirror (XCD L2)

  hipMemsetAsync(exs, 0, 2 * EXB, stream);          // fresh tags every call
  xproj_gemm<<<dim3(128, 8, 2), dim3(256), 0, stream>>>(x, WihF, bihF, WihB, bihB, xpw);
  lstm_rec<<<dim3(16), dim3(512), 0, stream>>>(WhhF, WhhB, xpw, out, exs, exf);
}

// Round 8
// 6078.972 us; speedup vs baseline: 1.0853x; 1.0853x over previous
//
#include <hip/hip_runtime.h>
#include <hip/hip_bf16.h>
#include <stdint.h>

#define SQ   2048
#define NB   8
#define G4   1024
#define NROW 16384   // SQ*NB

typedef float f32x4 __attribute__((ext_vector_type(4)));
typedef short bf16x8 __attribute__((ext_vector_type(8)));
typedef uint32_t u32;
typedef unsigned long long u64;

// ---------------- helpers ----------------
__device__ __forceinline__ f32x4 mfma16(bf16x8 a, bf16x8 b, f32x4 c) {
  return __builtin_amdgcn_mfma_f32_16x16x32_bf16(a, b, c, 0, 0, 0);
}
__device__ __forceinline__ u32 pk_bf16(float lo, float hi) {
  u32 r;
  asm("v_cvt_pk_bf16_f32 %0, %1, %2" : "=v"(r) : "v"(lo), "v"(hi));
  return r;
}
__device__ __forceinline__ float bf_lo(u32 u){ union{u32 a; float f;} x; x.a = u << 16;        return x.f; }
__device__ __forceinline__ float bf_hi(u32 u){ union{u32 a; float f;} x; x.a = u & 0xffff0000u; return x.f; }

__device__ __forceinline__ float sigm(float x)   { return 1.0f / (1.0f + __expf(-x)); }
__device__ __forceinline__ float tanh_f(float x) { return 1.0f - 2.0f / (__expf(2.0f * x) + 1.0f); }

// Opaque touch: forbids rematerialization of the weight fragments.
#define PIN(x) asm volatile("" : "+v"(x))

// Fast-mirror ops: sc0 = bypass L1, hit the XCD-shared L2. Tag-guarded with
// agent-scope (MALL) fallback, so cross-XCD placement stays correct.
__device__ __forceinline__ u64 ld_fast(const u64* p) {
  u64 v;
  asm volatile("global_load_dwordx2 %0, %1, off sc0\n\ts_waitcnt vmcnt(0)"
               : "=v"(v) : "v"(p) : "memory");
  return v;
}
__device__ __forceinline__ void st_fast(u64* p, u64 v) {
  asm volatile("global_store_dwordx2 %0, %1, off sc0" :: "v"(p), "v"(v) : "memory");
}

// =====================================================================
// Kernel 1: x_proj = x @ Wih^T + bih  -> bf16, layout [dir][m=t*8+b][1024]
// (unchanged from the version that passed R2/R5/R6/R7)
// =====================================================================
__global__ __launch_bounds__(256) void xproj_gemm(
    const float* __restrict__ x,
    const float* __restrict__ WihF, const float* __restrict__ bihF,
    const float* __restrict__ WihB, const float* __restrict__ bihB,
    uint16_t* __restrict__ xp)
{
  const int dir = blockIdx.z;
  const float* Wih = dir ? WihB : WihF;
  const float* bih = dir ? bihB : bihF;
  char* xpd = (char*)xp + (size_t)dir * ((size_t)NROW * G4 * 2);

  const int g0 = blockIdx.y * 128;
  const int m0 = blockIdx.x * 128;

  __shared__ union {
    struct { short A[128 * 72]; short B[128 * 72]; } s;  // 144B row pitch
    short T[128 * 136];                                  // transpose stage
  } u;
  __shared__ float biasS[128];

  const int tid  = threadIdx.x;
  const int lane = tid & 63;
  const int w    = tid >> 6;
  const int wg   = w >> 1;
  const int wm   = w & 1;
  const int l15  = lane & 15;
  const int l4   = lane >> 4;

  if (tid < 128) biasS[tid] = bih[g0 + tid];

  f32x4 acc[4][4] = {};

  const int r_st = tid >> 1;
  const int half = tid & 1;
  const int mrow_st = m0 + r_st;
  const int xb = mrow_st & 7;
  const int xt = mrow_st >> 3;
  const float* xrow = x + ((size_t)xb * SQ + xt) * 256;
  const float* wrow = Wih + (size_t)(g0 + r_st) * 256;

  for (int s = 0; s < 4; ++s) {
    const int k0 = s * 64;
    __syncthreads();
    {
      const float* srcA = wrow + k0 + half * 32;
      const float* srcB = xrow + k0 + half * 32;
      short* dstA = u.s.A + r_st * 72 + half * 32;
      short* dstB = u.s.B + r_st * 72 + half * 32;
      #pragma unroll
      for (int j = 0; j < 4; ++j) {
        f32x4 a0 = *(const f32x4*)(srcA + j * 8);
        f32x4 a1 = *(const f32x4*)(srcA + j * 8 + 4);
        uint4 pa = { pk_bf16(a0.x, a0.y), pk_bf16(a0.z, a0.w),
                     pk_bf16(a1.x, a1.y), pk_bf16(a1.z, a1.w) };
        *(uint4*)(dstA + j * 8) = pa;
        f32x4 b0 = *(const f32x4*)(srcB + j * 8);
        f32x4 b1 = *(const f32x4*)(srcB + j * 8 + 4);
        uint4 pb = { pk_bf16(b0.x, b0.y), pk_bf16(b0.z, b0.w),
                     pk_bf16(b1.x, b1.y), pk_bf16(b1.z, b1.w) };
        *(uint4*)(dstB + j * 8) = pb;
      }
    }
    __syncthreads();
    #pragma unroll
    for (int kt = 0; kt < 2; ++kt) {
      bf16x8 aF[4], bF[4];
      #pragma unroll
      for (int i = 0; i < 4; ++i) {
        const int ar = wg * 64 + i * 16 + l15;
        const int br = wm * 64 + i * 16 + l15;
        aF[i] = *(const bf16x8*)(u.s.A + ar * 72 + kt * 32 + l4 * 8);
        bF[i] = *(const bf16x8*)(u.s.B + br * 72 + kt * 32 + l4 * 8);
      }
      #pragma unroll
      for (int i = 0; i < 4; ++i)
        #pragma unroll
        for (int j = 0; j < 4; ++j)
          acc[i][j] = mfma16(aF[i], bF[j], acc[i][j]);
    }
  }

  __syncthreads();
  #pragma unroll
  for (int i = 0; i < 4; ++i) {
    const f32x4 bv = *(const f32x4*)(biasS + wg * 64 + i * 16 + l4 * 4);
    #pragma unroll
    for (int j = 0; j < 4; ++j) {
      f32x4 v = acc[i][j];
      v.x += bv.x; v.y += bv.y; v.z += bv.z; v.w += bv.w;
      const int mrow = wm * 64 + j * 16 + l15;
      const int gcol = wg * 64 + i * 16 + l4 * 4;
      uint2 p; p.x = pk_bf16(v.x, v.y); p.y = pk_bf16(v.z, v.w);
      *(uint2*)(u.T + mrow * 136 + gcol) = p;
    }
  }
  __syncthreads();
  {
    const char* trow = (const char*)(u.T + r_st * 136);
    char* orow = xpd + (size_t)(m0 + r_st) * 2048 + g0 * 2;
    #pragma unroll
    for (int j = 0; j < 8; ++j) {
      const int local = half * 128 + j * 16;
      uint4 v = *(const uint4*)(trow + local);
      *(uint4*)(orow + local) = v;
    }
  }
}

// =====================================================================
// Kernel 2: BiLSTM scan. 4 WGs/dir (8 CUs), 256 thr = 4 waves at
// __launch_bounds__(256,1) — the EXACT config that held weights resident
// in R5 (VGPR=144). Wave w of chunk-WG c owns all 4 gates x 16 h-dims
// (rows g*256 + c*64 + w*16): W[4][8] = 128 VGPRs, PINned. Per step per
// lane: publish ONE {2bf16|tag} u64 (fast sc0 + slow agent mirrors),
// poll THREE partner-chunk words (batched loads, coalesced), stage to a
// full-h LDS buffer shared by all waves. One s_barrier + lgkmcnt(0) per
// step. 32 builtin MFMAs/wave; wave-local epilogue (2 dims/lane).
// dir = bid&7 -> all 4 chunk-WGs of a dir on one XCD (round-robin);
// fast mirror falls back to agent scope if the heuristic fails.
// =====================================================================
__global__ __launch_bounds__(256, 1) void lstm_rec(
    const float* __restrict__ WhhF, const float* __restrict__ WhhB,
    const uint16_t* __restrict__ xp, float* __restrict__ out,
    u64* exs, u64* exf)
{
  __shared__ alignas(16) uint16_t hF[2][8][264];   // full h, 2 slots, 528B pitch

  const int bid = blockIdx.x;
  const int dir = bid & 7;
  const int c   = bid >> 3;            // h-dim chunk 0..3
  if (dir > 1) return;                 // 24 idle blocks exit

  const float* Whh = dir ? WhhB : WhhF;
  const uint16_t* xpd = xp + (size_t)dir * NROW * G4;

  const int tid  = threadIdx.x;
  const int lane = tid & 63;
  const int w    = tid >> 6;          // wave 0..3
  const int l15  = lane & 15;
  const int l4   = lane >> 4;
  const int bcl  = lane & 7;          // batch this lane serves
  const int qsel = (lane >> 3) & 1;   // duplicate-column half select

  // ---- persistent weights: gate g, k-block kt; rows g*256 + c*64 + w*16
  bf16x8 W[4][8];
  #pragma unroll
  for (int g = 0; g < 4; ++g) {
    const int row = g * 256 + c * 64 + w * 16 + l15;
    const float* src = Whh + (size_t)row * 256 + l4 * 8;
    #pragma unroll
    for (int kt = 0; kt < 8; ++kt) {
      f32x4 v0 = *(const f32x4*)(src + kt * 32);
      f32x4 v1 = *(const f32x4*)(src + kt * 32 + 4);
      union { bf16x8 v; u32 u[4]; } pk;
      pk.u[0] = pk_bf16(v0.x, v0.y); pk.u[1] = pk_bf16(v0.z, v0.w);
      pk.u[2] = pk_bf16(v1.x, v1.y); pk.u[3] = pk_bf16(v1.z, v1.w);
      W[g][kt] = pk.v;
      PIN(W[g][kt]);
    }
  }

  // mirror layout: [dir][chunk][slot][256 words]
  u64* exf_me = exf + (size_t)(dir * 4 + c) * 512;
  u64* exs_me = exs + (size_t)(dir * 4 + c) * 512;
  const u64* pf[3]; const u64* ps[3];
  #pragma unroll
  for (int j = 0; j < 3; ++j) {
    const int cc = (c + 1 + j) & 3;
    pf[j] = exf + (size_t)(dir * 4 + cc) * 512;
    ps[j] = exs + (size_t)(dir * 4 + cc) * 512;
  }
  const int cc0 = ((c + 1) & 3) * 64, cc1 = ((c + 2) & 3) * 64, cc2 = ((c + 3) & 3) * 64;
  const int sb = tid >> 5, sp2 = (tid & 31) * 2;   // staging (batch, dim-pair*2)

  const int d0   = w * 16 + l4 * 4 + qsel * 2;     // chunk-local dim pair
  const int word = bcl * 32 + (d0 >> 1);           // publish word (bijective)
  float c0 = 0.0f, c1 = 0.0f;

  // prologue: xp for step 0 (2 bf16 per gate)
  u32 xq[4], xqn[4];
  {
    const int tt0 = dir ? SQ - 1 : 0;
    const uint16_t* xr = xpd + (size_t)(tt0 * 8 + bcl) * 1024 + c * 64 + d0;
    #pragma unroll
    for (int g = 0; g < 4; ++g) xq[g] = *(const u32*)(xr + g * 256);
  }

  int slowMode = 0, slowWins = 0;

  #pragma unroll 1
  for (int t = 0; t < SQ; ++t) {
    const int tt = dir ? (SQ - 1 - t) : t;

    // ---- poll 3 partner words, stage into LDS slot (t-1)&1
    if (t > 0) {
      const u32 want = (u32)t;
      const size_t soff = (size_t)((t - 1) & 1) * 256 + tid;
      u64 pw0, pw1, pw2;
      if (!slowMode) {
        asm volatile(
          "global_load_dwordx2 %0, %3, off sc0\n\t"
          "global_load_dwordx2 %1, %4, off sc0\n\t"
          "global_load_dwordx2 %2, %5, off sc0\n\t"
          "s_waitcnt vmcnt(0)"
          : "=v"(pw0), "=v"(pw1), "=v"(pw2)
          : "v"(pf[0] + soff), "v"(pf[1] + soff), "v"(pf[2] + soff)
          : "memory");
      } else {
        pw0 = __hip_atomic_load(ps[0] + soff, __ATOMIC_RELAXED, __HIP_MEMORY_SCOPE_AGENT);
        pw1 = __hip_atomic_load(ps[1] + soff, __ATOMIC_RELAXED, __HIP_MEMORY_SCOPE_AGENT);
        pw2 = __hip_atomic_load(ps[2] + soff, __ATOMIC_RELAXED, __HIP_MEMORY_SCOPE_AGENT);
      }
      int anySlow = 0;
      #pragma unroll
      for (int j = 0; j < 3; ++j) {
        u64& pw = (j == 0) ? pw0 : (j == 1) ? pw1 : pw2;
        int tries = 0;
        while ((u32)pw != want) {
          ++tries;
          if (slowMode || tries > 8) {
            anySlow = 1;
            pw = __hip_atomic_load(ps[j] + soff, __ATOMIC_RELAXED,
                                   __HIP_MEMORY_SCOPE_AGENT);
          } else {
            pw = ld_fast(pf[j] + soff);
          }
        }
      }
      if (!slowMode && anySlow) { if (++slowWins >= 4) slowMode = 1; }

      uint16_t* hrow = &hF[(t - 1) & 1][sb][0];
      *(u32*)(hrow + cc0 + sp2) = (u32)(pw0 >> 32);
      *(u32*)(hrow + cc1 + sp2) = (u32)(pw1 >> 32);
      *(u32*)(hrow + cc2 + sp2) = (u32)(pw2 >> 32);
    }
    asm volatile("s_waitcnt lgkmcnt(0)" ::: "memory");
    __builtin_amdgcn_s_barrier();

    // ---- issue next step's xp loads (latency hides under MFMA+epilogue)
    {
      const int tn = (t + 1 < SQ) ? t + 1 : SQ - 1;
      const int ttn = dir ? (SQ - 1 - tn) : tn;
      const uint16_t* xr = xpd + (size_t)(ttn * 8 + bcl) * 1024 + c * 64 + d0;
      #pragma unroll
      for (int g = 0; g < 4; ++g) xqn[g] = *(const u32*)(xr + g * 256);
    }

    // ---- gates = Whh * h : 32 builtin MFMAs, B-frags from LDS full-h
    f32x4 acc[4] = {};
    if (t > 0) {
      #pragma unroll
      for (int kt = 0; kt < 8; ++kt) {
        const bf16x8 bF = *(const bf16x8*)&hF[(t - 1) & 1][bcl][kt * 32 + l4 * 8];
        #pragma unroll
        for (int g = 0; g < 4; ++g) acc[g] = mfma16(W[g][kt], bF, acc[g]);
      }
    }

    // ---- epilogue (wave-local; qsel picks duplicate-column elements)
    float P0[4], P1[4];
    #pragma unroll
    for (int g = 0; g < 4; ++g) {
      P0[g] = (qsel ? acc[g].z : acc[g].x) + bf_lo(xq[g]);
      P1[g] = (qsel ? acc[g].w : acc[g].y) + bf_hi(xq[g]);
    }
    const float i0 = sigm(P0[0]), f0 = sigm(P0[1]), g0v = tanh_f(P0[2]), o0 = sigm(P0[3]);
    const float i1 = sigm(P1[0]), f1 = sigm(P1[1]), g1v = tanh_f(P1[2]), o1 = sigm(P1[3]);
    c0 = f0 * c0 + i0 * g0v;
    c1 = f1 * c1 + i1 * g1v;
    const float h0 = o0 * tanh_f(c0);
    const float h1 = o1 * tanh_f(c1);

    // ---- publish FIRST (partner critical path), then LDS own-chunk, then out
    const u32 h01 = pk_bf16(h0, h1);
    const u64 pub = ((u64)h01 << 32) | (u64)(u32)(t + 1);
    st_fast(exf_me + (size_t)(t & 1) * 256 + word, pub);
    __hip_atomic_store(exs_me + (size_t)(t & 1) * 256 + word, pub,
                       __ATOMIC_RELAXED, __HIP_MEMORY_SCOPE_AGENT);
    *(u32*)&hF[t & 1][bcl][c * 64 + d0] = h01;
    *(float2*)(out + ((size_t)bcl * SQ + tt) * 512 + dir * 256 + c * 64 + d0) =
        make_float2(h0, h1);

    #pragma unroll
    for (int g = 0; g < 4; ++g) xq[g] = xqn[g];
  }
}

// =====================================================================
extern "C" void kernel_launch(void* const* d_in, const int* in_sizes, int n_in,
                              void* d_out, int out_size, void* d_ws, size_t ws_size,
                              hipStream_t stream) {
  const float* x    = (const float*)d_in[0];
  const float* WihF = (const float*)d_in[1];
  const float* bihF = (const float*)d_in[2];
  const float* WhhF = (const float*)d_in[3];
  const float* WihB = (const float*)d_in[4];
  const float* bihB = (const float*)d_in[5];
  const float* WhhB = (const float*)d_in[6];
  float* out = (float*)d_out;

  const size_t XPB = (size_t)2 * NROW * G4 * 2;     // 64 MiB bf16 x-projection
  const size_t EXB = (size_t)4096 * sizeof(u64);    // 32 KiB per mirror
  if (ws_size < XPB + 2 * EXB) return;
  uint16_t* xpw = (uint16_t*)d_ws;
  u64* exs = (u64*)((char*)d_ws + XPB);             // slow mirror (agent/MALL)
  u64* exf = (u64*)((char*)d_ws + XPB + EXB);       // fast mirror (XCD L2)

  hipMemsetAsync(exs, 0, 2 * EXB, stream);          // fresh tags every call
  xproj_gemm<<<dim3(128, 8, 2), dim3(256), 0, stream>>>(x, WihF, bihF, WihB, bihB, xpw);
  lstm_rec<<<dim3(32), dim3(256), 0, stream>>>(WhhF, WhhB, xpw, out, exs, exf);
}

// Round 9
// 6057.429 us; speedup vs baseline: 1.0891x; 1.0036x over previous
//
#include <hip/hip_runtime.h>
#include <hip/hip_bf16.h>
#include <stdint.h>

#define SQ   2048
#define NB   8
#define G4   1024
#define NROW 16384   // SQ*NB

typedef float f32x4 __attribute__((ext_vector_type(4)));
typedef short bf16x8 __attribute__((ext_vector_type(8)));
typedef uint32_t u32;
typedef unsigned long long u64;

// ---------------- helpers ----------------
__device__ __forceinline__ f32x4 mfma16(bf16x8 a, bf16x8 b, f32x4 c) {
  return __builtin_amdgcn_mfma_f32_16x16x32_bf16(a, b, c, 0, 0, 0);
}
__device__ __forceinline__ u32 pk_bf16(float lo, float hi) {
  u32 r;
  asm("v_cvt_pk_bf16_f32 %0, %1, %2" : "=v"(r) : "v"(lo), "v"(hi));
  return r;
}
__device__ __forceinline__ float bf_lo(u32 u){ union{u32 a; float f;} x; x.a = u << 16;        return x.f; }
__device__ __forceinline__ float bf_hi(u32 u){ union{u32 a; float f;} x; x.a = u & 0xffff0000u; return x.f; }

__device__ __forceinline__ float sigm(float x)   { return 1.0f / (1.0f + __expf(-x)); }
__device__ __forceinline__ float tanh_f(float x) { return 1.0f - 2.0f / (__expf(2.0f * x) + 1.0f); }

// AGPR pin: force the value's home into the (otherwise idle) accumulator
// file. Def becomes inline asm (cannot remat), AGPR pressure stays far
// below budget (no spill incentive), and gfx950 MFMA reads AGPR SrcA
// directly (or via cheap v_accvgpr_read copies). R6-R8 showed the arch-
// VGPR allocator refuses a 128-reg loop-carried weight live range.
// NOTE: this is an empty annotation at init only — all MFMAs remain
// builtins with compiler-managed hazards (the R3/R4 trap does not apply).
#define PINA(x) asm volatile("" : "+a"(x))

// Fast-mirror ops: sc0 = bypass L1, hit the XCD-shared L2. Tag-guarded with
// agent-scope (MALL) fallback, so cross-XCD placement stays correct.
__device__ __forceinline__ u64 ld_fast(const u64* p) {
  u64 v;
  asm volatile("global_load_dwordx2 %0, %1, off sc0\n\ts_waitcnt vmcnt(0)"
               : "=v"(v) : "v"(p) : "memory");
  return v;
}
__device__ __forceinline__ void st_fast(u64* p, u64 v) {
  asm volatile("global_store_dwordx2 %0, %1, off sc0" :: "v"(p), "v"(v) : "memory");
}

// =====================================================================
// Kernel 1: x_proj = x @ Wih^T + bih  -> bf16, layout [dir][m=t*8+b][1024]
// (unchanged from the version that passed R2/R5/R6/R7/R8)
// =====================================================================
__global__ __launch_bounds__(256) void xproj_gemm(
    const float* __restrict__ x,
    const float* __restrict__ WihF, const float* __restrict__ bihF,
    const float* __restrict__ WihB, const float* __restrict__ bihB,
    uint16_t* __restrict__ xp)
{
  const int dir = blockIdx.z;
  const float* Wih = dir ? WihB : WihF;
  const float* bih = dir ? bihB : bihF;
  char* xpd = (char*)xp + (size_t)dir * ((size_t)NROW * G4 * 2);

  const int g0 = blockIdx.y * 128;
  const int m0 = blockIdx.x * 128;

  __shared__ union {
    struct { short A[128 * 72]; short B[128 * 72]; } s;  // 144B row pitch
    short T[128 * 136];                                  // transpose stage
  } u;
  __shared__ float biasS[128];

  const int tid  = threadIdx.x;
  const int lane = tid & 63;
  const int w    = tid >> 6;
  const int wg   = w >> 1;
  const int wm   = w & 1;
  const int l15  = lane & 15;
  const int l4   = lane >> 4;

  if (tid < 128) biasS[tid] = bih[g0 + tid];

  f32x4 acc[4][4] = {};

  const int r_st = tid >> 1;
  const int half = tid & 1;
  const int mrow_st = m0 + r_st;
  const int xb = mrow_st & 7;
  const int xt = mrow_st >> 3;
  const float* xrow = x + ((size_t)xb * SQ + xt) * 256;
  const float* wrow = Wih + (size_t)(g0 + r_st) * 256;

  for (int s = 0; s < 4; ++s) {
    const int k0 = s * 64;
    __syncthreads();
    {
      const float* srcA = wrow + k0 + half * 32;
      const float* srcB = xrow + k0 + half * 32;
      short* dstA = u.s.A + r_st * 72 + half * 32;
      short* dstB = u.s.B + r_st * 72 + half * 32;
      #pragma unroll
      for (int j = 0; j < 4; ++j) {
        f32x4 a0 = *(const f32x4*)(srcA + j * 8);
        f32x4 a1 = *(const f32x4*)(srcA + j * 8 + 4);
        uint4 pa = { pk_bf16(a0.x, a0.y), pk_bf16(a0.z, a0.w),
                     pk_bf16(a1.x, a1.y), pk_bf16(a1.z, a1.w) };
        *(uint4*)(dstA + j * 8) = pa;
        f32x4 b0 = *(const f32x4*)(srcB + j * 8);
        f32x4 b1 = *(const f32x4*)(srcB + j * 8 + 4);
        uint4 pb = { pk_bf16(b0.x, b0.y), pk_bf16(b0.z, b0.w),
                     pk_bf16(b1.x, b1.y), pk_bf16(b1.z, b1.w) };
        *(uint4*)(dstB + j * 8) = pb;
      }
    }
    __syncthreads();
    #pragma unroll
    for (int kt = 0; kt < 2; ++kt) {
      bf16x8 aF[4], bF[4];
      #pragma unroll
      for (int i = 0; i < 4; ++i) {
        const int ar = wg * 64 + i * 16 + l15;
        const int br = wm * 64 + i * 16 + l15;
        aF[i] = *(const bf16x8*)(u.s.A + ar * 72 + kt * 32 + l4 * 8);
        bF[i] = *(const bf16x8*)(u.s.B + br * 72 + kt * 32 + l4 * 8);
      }
      #pragma unroll
      for (int i = 0; i < 4; ++i)
        #pragma unroll
        for (int j = 0; j < 4; ++j)
          acc[i][j] = mfma16(aF[i], bF[j], acc[i][j]);
    }
  }

  __syncthreads();
  #pragma unroll
  for (int i = 0; i < 4; ++i) {
    const f32x4 bv = *(const f32x4*)(biasS + wg * 64 + i * 16 + l4 * 4);
    #pragma unroll
    for (int j = 0; j < 4; ++j) {
      f32x4 v = acc[i][j];
      v.x += bv.x; v.y += bv.y; v.z += bv.z; v.w += bv.w;
      const int mrow = wm * 64 + j * 16 + l15;
      const int gcol = wg * 64 + i * 16 + l4 * 4;
      uint2 p; p.x = pk_bf16(v.x, v.y); p.y = pk_bf16(v.z, v.w);
      *(uint2*)(u.T + mrow * 136 + gcol) = p;
    }
  }
  __syncthreads();
  {
    const char* trow = (const char*)(u.T + r_st * 136);
    char* orow = xpd + (size_t)(m0 + r_st) * 2048 + g0 * 2;
    #pragma unroll
    for (int j = 0; j < 8; ++j) {
      const int local = half * 128 + j * 16;
      uint4 v = *(const uint4*)(trow + local);
      *(uint4*)(orow + local) = v;
    }
  }
}

// =====================================================================
// Kernel 2: BiLSTM scan. 4 WGs/dir (8 CUs), 256 thr = 4 waves,
// __launch_bounds__(256,1). Wave w of chunk-WG c owns all 4 gates x 16
// h-dims: W[4][8] = 128 regs — pinned into the AGPR FILE (PINA), which
// the arch-VGPR allocator cannot touch (R6-R8: it re-streamed 256KB/step
// from L2 instead of keeping weights resident = the ~4300cyc/step
// bottleneck). Exchange per lane per step: publish ONE {2bf16|tag} u64
// (fast sc0 + slow agent mirrors), poll THREE partner-chunk words
// (batched), stage to full-h LDS shared by all waves. One s_barrier +
// lgkmcnt(0) per step; 32 builtin MFMAs; wave-local epilogue.
// dir = bid&7 -> all 4 chunk-WGs of a dir on one XCD (round-robin);
// fast mirror falls back to agent scope if the heuristic fails.
// =====================================================================
__global__ __launch_bounds__(256, 1) void lstm_rec(
    const float* __restrict__ WhhF, const float* __restrict__ WhhB,
    const uint16_t* __restrict__ xp, float* __restrict__ out,
    u64* exs, u64* exf)
{
  __shared__ alignas(16) uint16_t hF[2][8][264];   // full h, 2 slots, 528B pitch

  const int bid = blockIdx.x;
  const int dir = bid & 7;
  const int c   = bid >> 3;            // h-dim chunk 0..3
  if (dir > 1) return;                 // 24 idle blocks exit

  const float* Whh = dir ? WhhB : WhhF;
  const uint16_t* xpd = xp + (size_t)dir * NROW * G4;

  const int tid  = threadIdx.x;
  const int lane = tid & 63;
  const int w    = tid >> 6;          // wave 0..3
  const int l15  = lane & 15;
  const int l4   = lane >> 4;
  const int bcl  = lane & 7;          // batch this lane serves
  const int qsel = (lane >> 3) & 1;   // duplicate-column half select

  // ---- persistent weights: gate g, k-block kt; rows g*256 + c*64 + w*16
  // Home = AGPR file (PINA). MFMA SrcA reads AGPR directly on gfx950
  // (or via v_accvgpr_read copies — either way, zero memory traffic).
  bf16x8 W[4][8];
  #pragma unroll
  for (int g = 0; g < 4; ++g) {
    const int row = g * 256 + c * 64 + w * 16 + l15;
    const float* src = Whh + (size_t)row * 256 + l4 * 8;
    #pragma unroll
    for (int kt = 0; kt < 8; ++kt) {
      f32x4 v0 = *(const f32x4*)(src + kt * 32);
      f32x4 v1 = *(const f32x4*)(src + kt * 32 + 4);
      union { bf16x8 v; u32 u[4]; } pk;
      pk.u[0] = pk_bf16(v0.x, v0.y); pk.u[1] = pk_bf16(v0.z, v0.w);
      pk.u[2] = pk_bf16(v1.x, v1.y); pk.u[3] = pk_bf16(v1.z, v1.w);
      W[g][kt] = pk.v;
      PINA(W[g][kt]);
    }
  }

  // mirror layout: [dir][chunk][slot][256 words]
  u64* exf_me = exf + (size_t)(dir * 4 + c) * 512;
  u64* exs_me = exs + (size_t)(dir * 4 + c) * 512;
  const u64* pf[3]; const u64* ps[3];
  #pragma unroll
  for (int j = 0; j < 3; ++j) {
    const int cc = (c + 1 + j) & 3;
    pf[j] = exf + (size_t)(dir * 4 + cc) * 512;
    ps[j] = exs + (size_t)(dir * 4 + cc) * 512;
  }
  const int cc0 = ((c + 1) & 3) * 64, cc1 = ((c + 2) & 3) * 64, cc2 = ((c + 3) & 3) * 64;
  const int sb = tid >> 5, sp2 = (tid & 31) * 2;   // staging (batch, dim-pair*2)

  const int d0   = w * 16 + l4 * 4 + qsel * 2;     // chunk-local dim pair
  const int word = bcl * 32 + (d0 >> 1);           // publish word (bijective)
  float c0 = 0.0f, c1 = 0.0f;

  // prologue: xp for step 0 (2 bf16 per gate)
  u32 xq[4], xqn[4];
  {
    const int tt0 = dir ? SQ - 1 : 0;
    const uint16_t* xr = xpd + (size_t)(tt0 * 8 + bcl) * 1024 + c * 64 + d0;
    #pragma unroll
    for (int g = 0; g < 4; ++g) xq[g] = *(const u32*)(xr + g * 256);
  }

  int slowMode = 0, slowWins = 0;

  #pragma unroll 1
  for (int t = 0; t < SQ; ++t) {
    const int tt = dir ? (SQ - 1 - t) : t;

    // ---- poll 3 partner words, stage into LDS slot (t-1)&1
    if (t > 0) {
      const u32 want = (u32)t;
      const size_t soff = (size_t)((t - 1) & 1) * 256 + tid;
      u64 pw0, pw1, pw2;
      if (!slowMode) {
        asm volatile(
          "global_load_dwordx2 %0, %3, off sc0\n\t"
          "global_load_dwordx2 %1, %4, off sc0\n\t"
          "global_load_dwordx2 %2, %5, off sc0\n\t"
          "s_waitcnt vmcnt(0)"
          : "=v"(pw0), "=v"(pw1), "=v"(pw2)
          : "v"(pf[0] + soff), "v"(pf[1] + soff), "v"(pf[2] + soff)
          : "memory");
      } else {
        pw0 = __hip_atomic_load(ps[0] + soff, __ATOMIC_RELAXED, __HIP_MEMORY_SCOPE_AGENT);
        pw1 = __hip_atomic_load(ps[1] + soff, __ATOMIC_RELAXED, __HIP_MEMORY_SCOPE_AGENT);
        pw2 = __hip_atomic_load(ps[2] + soff, __ATOMIC_RELAXED, __HIP_MEMORY_SCOPE_AGENT);
      }
      int anySlow = 0;
      #pragma unroll
      for (int j = 0; j < 3; ++j) {
        u64& pw = (j == 0) ? pw0 : (j == 1) ? pw1 : pw2;
        int tries = 0;
        while ((u32)pw != want) {
          ++tries;
          if (slowMode || tries > 8) {
            anySlow = 1;
            pw = __hip_atomic_load(ps[j] + soff, __ATOMIC_RELAXED,
                                   __HIP_MEMORY_SCOPE_AGENT);
          } else {
            pw = ld_fast(pf[j] + soff);
          }
        }
      }
      if (!slowMode && anySlow) { if (++slowWins >= 4) slowMode = 1; }

      uint16_t* hrow = &hF[(t - 1) & 1][sb][0];
      *(u32*)(hrow + cc0 + sp2) = (u32)(pw0 >> 32);
      *(u32*)(hrow + cc1 + sp2) = (u32)(pw1 >> 32);
      *(u32*)(hrow + cc2 + sp2) = (u32)(pw2 >> 32);
    }
    asm volatile("s_waitcnt lgkmcnt(0)" ::: "memory");
    __builtin_amdgcn_s_barrier();

    // ---- issue next step's xp loads (latency hides under MFMA+epilogue)
    {
      const int tn = (t + 1 < SQ) ? t + 1 : SQ - 1;
      const int ttn = dir ? (SQ - 1 - tn) : tn;
      const uint16_t* xr = xpd + (size_t)(ttn * 8 + bcl) * 1024 + c * 64 + d0;
      #pragma unroll
      for (int g = 0; g < 4; ++g) xqn[g] = *(const u32*)(xr + g * 256);
    }

    // ---- gates = Whh * h : 32 builtin MFMAs, B-frags from LDS full-h
    f32x4 acc[4] = {};
    if (t > 0) {
      #pragma unroll
      for (int kt = 0; kt < 8; ++kt) {
        const bf16x8 bF = *(const bf16x8*)&hF[(t - 1) & 1][bcl][kt * 32 + l4 * 8];
        #pragma unroll
        for (int g = 0; g < 4; ++g) acc[g] = mfma16(W[g][kt], bF, acc[g]);
      }
    }

    // ---- epilogue (wave-local; qsel picks duplicate-column elements)
    float P0[4], P1[4];
    #pragma unroll
    for (int g = 0; g < 4; ++g) {
      P0[g] = (qsel ? acc[g].z : acc[g].x) + bf_lo(xq[g]);
      P1[g] = (qsel ? acc[g].w : acc[g].y) + bf_hi(xq[g]);
    }
    const float i0 = sigm(P0[0]), f0 = sigm(P0[1]), g0v = tanh_f(P0[2]), o0 = sigm(P0[3]);
    const float i1 = sigm(P1[0]), f1 = sigm(P1[1]), g1v = tanh_f(P1[2]), o1 = sigm(P1[3]);
    c0 = f0 * c0 + i0 * g0v;
    c1 = f1 * c1 + i1 * g1v;
    const float h0 = o0 * tanh_f(c0);
    const float h1 = o1 * tanh_f(c1);

    // ---- publish FIRST (partner critical path), then LDS own-chunk, then out
    const u32 h01 = pk_bf16(h0, h1);
    const u64 pub = ((u64)h01 << 32) | (u64)(u32)(t + 1);
    st_fast(exf_me + (size_t)(t & 1) * 256 + word, pub);
    __hip_atomic_store(exs_me + (size_t)(t & 1) * 256 + word, pub,
                       __ATOMIC_RELAXED, __HIP_MEMORY_SCOPE_AGENT);
    *(u32*)&hF[t & 1][bcl][c * 64 + d0] = h01;
    *(float2*)(out + ((size_t)bcl * SQ + tt) * 512 + dir * 256 + c * 64 + d0) =
        make_float2(h0, h1);

    #pragma unroll
    for (int g = 0; g < 4; ++g) xq[g] = xqn[g];
  }
}

// =====================================================================
extern "C" void kernel_launch(void* const* d_in, const int* in_sizes, int n_in,
                              void* d_out, int out_size, void* d_ws, size_t ws_size,
                              hipStream_t stream) {
  const float* x    = (const float*)d_in[0];
  const float* WihF = (const float*)d_in[1];
  const float* bihF = (const float*)d_in[2];
  const float* WhhF = (const float*)d_in[3];
  const float* WihB = (const float*)d_in[4];
  const float* bihB = (const float*)d_in[5];
  const float* WhhB = (const float*)d_in[6];
  float* out = (float*)d_out;

  const size_t XPB = (size_t)2 * NROW * G4 * 2;     // 64 MiB bf16 x-projection
  const size_t EXB = (size_t)4096 * sizeof(u64);    // 32 KiB per mirror
  if (ws_size < XPB + 2 * EXB) return;
  uint16_t* xpw = (uint16_t*)d_ws;
  u64* exs = (u64*)((char*)d_ws + XPB);             // slow mirror (agent/MALL)
  u64* exf = (u64*)((char*)d_ws + XPB + EXB);       // fast mirror (XCD L2)

  hipMemsetAsync(exs, 0, 2 * EXB, stream);          // fresh tags every call
  xproj_gemm<<<dim3(128, 8, 2), dim3(256), 0, stream>>>(x, WihF, bihF, WihB, bihB, xpw);
  lstm_rec<<<dim3(32), dim3(256), 0, stream>>>(WhhF, WhhB, xpw, out, exs, exf);
}